// Round 9
// baseline (515.518 us; speedup 1.0000x reference)
//
#include <hip/hip_runtime.h>
#include <hip/hip_bf16.h>
#include <cstdint>
#include <cstddef>

// Problem constants (B=1)
#define EN 400000   // edges
#define NN 25000    // nodes
// D=128, H=4, DK=DV=32

typedef __attribute__((ext_vector_type(8))) short bf16x8;
typedef __attribute__((ext_vector_type(4))) short bf16x4;
typedef __attribute__((ext_vector_type(4))) float f32x4;

__device__ __forceinline__ short f2bf(float f) {
    unsigned int u = __float_as_uint(f);
    u = (u + 0x7fffu + ((u >> 16) & 1u)) >> 16;   // RNE
    return (short)u;
}
__device__ __forceinline__ float bf2f(short s) {
    return __uint_as_float(((unsigned int)(unsigned short)s) << 16);
}

// Identity ds_bpermute: result is DS-defined, so the compiler cannot rematerialize
// it from the original global load -> weight fragments stay register-resident.
__device__ __forceinline__ bf16x8 pin8(bf16x8 v) {
    union { bf16x8 s; int i[4]; } u; u.s = v;
    const int a = (threadIdx.x & 63) << 2;
#pragma unroll
    for (int k = 0; k < 4; ++k) u.i[k] = __builtin_amdgcn_ds_bpermute(a, u.i[k]);
    return u.s;
}

// ---------------- K0: fused weights->bf16 (hi 5 mats, lo 3 mats) + degree histogram ---
__global__ __launch_bounds__(256) void convert_hist_kernel(
    const float* __restrict__ w0, const float* __restrict__ w1,
    const float* __restrict__ w2, const float* __restrict__ w3,
    const float* __restrict__ w4, short* __restrict__ hi, short* __restrict__ lo,
    const int* __restrict__ eidx, int* __restrict__ deg)
{
    if (blockIdx.x < 512) {
        int i = blockIdx.x * 256 + threadIdx.x;      // 131072 threads
        if (i < 81920) {
            int w = i >> 14, off = i & 16383;
            const float* src = (w == 0) ? w0 : (w == 1) ? w1 : (w == 2) ? w2 : (w == 3) ? w3 : w4;
            hi[i] = f2bf(src[off]);
        } else {
            int j = i - 81920;                       // WQ, WK, WE lo parts
            int m = j >> 14, off = j & 16383;
            const float* src = (m == 0) ? w0 : (m == 1) ? w1 : w3;
            float x = src[off];
            short h = f2bf(x);
            lo[j] = f2bf(x - bf2f(h));
        }
    } else {
        int e = (blockIdx.x - 512) * 256 + threadIdx.x;
        if (e < EN) atomicAdd(&deg[eidx[e]], 1);
    }
}

// ---------------- CSR scan ----------------
__global__ __launch_bounds__(1024) void scan_kernel(
    const int* __restrict__ deg, int* __restrict__ base)
{
    __shared__ int part[1024];
    const int t = threadIdx.x;
    const int CH = 25;                       // 1024*25 = 25600 >= NN
    int loc[CH];
    int s = 0;
#pragma unroll
    for (int i = 0; i < CH; ++i) {
        int idx = t * CH + i;
        loc[i] = s;
        s += (idx < NN) ? deg[idx] : 0;
    }
    part[t] = s;
    __syncthreads();
    for (int d = 1; d < 1024; d <<= 1) {
        int v = (t >= d) ? part[t - d] : 0;
        __syncthreads();
        part[t] += v;
        __syncthreads();
    }
    int off = (t > 0) ? part[t - 1] : 0;
#pragma unroll
    for (int i = 0; i < CH; ++i) {
        int idx = t * CH + i;
        if (idx < NN) base[idx] = off + loc[i];
    }
    if (t == 1023) base[NN] = part[1023];
}

// writes pack[e] = {src, tgt, csr_pos, 0} and tgt_csr[csr_pos] = tgt
__global__ __launch_bounds__(256) void scatter_kernel(
    const int* __restrict__ eidx, const int* __restrict__ base,
    int* __restrict__ cnt, int4* __restrict__ pack, int* __restrict__ tgt_csr)
{
    int e = blockIdx.x * 256 + threadIdx.x;
    if (e < EN) {
        int s = eidx[e];
        int tg = eidx[EN + e];
        int p = base[s] + atomicAdd(&cnt[s], 1);
        pack[e] = make_int4(s, tg, p, 0);
        tgt_csr[p] = tg;
    }
}

// ---------------- K1: fused head-split projections (Q,K split-precision; V bf16) ------
// blockIdx.y: 0=Q, 1=K, 2=V. Wave hw = head hw: outdims [32hw, 32hw+32).
__global__ __launch_bounds__(256, 4) void proj_all_kernel(
    const float* __restrict__ inQ, const float* __restrict__ inK,
    const float* __restrict__ inV,
    const short* __restrict__ WhiBase, const short* __restrict__ WloBase,
    float* __restrict__ Qf, float* __restrict__ Kf, short* __restrict__ Vb)
{
    const int mode = blockIdx.y;
    const int lane = threadIdx.x & 63;
    const int hw = threadIdx.x >> 6;          // head / wave
    const int el = lane & 15;
    const int g  = lane >> 4;
    const int ntiles = (NN + 15) >> 4;

    if (mode < 2) {
        const float* X = mode ? inK : inQ;
        const short* Whi = WhiBase + mode * 16384;
        const short* Wlo = WloBase + mode * 16384;
        float* P = mode ? Kf : Qf;

        bf16x8 wh[2][4], wl[2][4];
#pragma unroll
        for (int dtt = 0; dtt < 2; ++dtt)
#pragma unroll
            for (int kc = 0; kc < 4; ++kc) {
                const int r = hw * 32 + dtt * 16 + el;
                const int c = kc * 32 + g * 8;
                wh[dtt][kc] = pin8(*(const bf16x8*)(Whi + r * 128 + c));
                wl[dtt][kc] = pin8(*(const bf16x8*)(Wlo + r * 128 + c));
            }

        for (int tile = blockIdx.x; tile < ntiles; tile += gridDim.x) {
            const int row = tile * 16 + el;
            const int rc = row < NN ? row : NN - 1;
            const float* xrow = X + (size_t)rc * 128;
            f32x4 acc0 = {}, acc1 = {};
#pragma unroll
            for (int kc = 0; kc < 4; ++kc) {
                const int kb = kc * 32 + g * 8;
                f32x4 x0 = *(const f32x4*)(xrow + kb);
                f32x4 x1 = *(const f32x4*)(xrow + kb + 4);
                bf16x8 bh, bl;
#pragma unroll
                for (int j = 0; j < 4; ++j) {
                    bh[j] = f2bf(x0[j]); bl[j] = f2bf(x0[j] - bf2f(bh[j]));
                    bh[4 + j] = f2bf(x1[j]); bl[4 + j] = f2bf(x1[j] - bf2f(bh[4 + j]));
                }
                acc0 = __builtin_amdgcn_mfma_f32_16x16x32_bf16(wh[0][kc], bh, acc0, 0, 0, 0);
                acc0 = __builtin_amdgcn_mfma_f32_16x16x32_bf16(wh[0][kc], bl, acc0, 0, 0, 0);
                acc0 = __builtin_amdgcn_mfma_f32_16x16x32_bf16(wl[0][kc], bh, acc0, 0, 0, 0);
                acc1 = __builtin_amdgcn_mfma_f32_16x16x32_bf16(wh[1][kc], bh, acc1, 0, 0, 0);
                acc1 = __builtin_amdgcn_mfma_f32_16x16x32_bf16(wh[1][kc], bl, acc1, 0, 0, 0);
                acc1 = __builtin_amdgcn_mfma_f32_16x16x32_bf16(wl[1][kc], bh, acc1, 0, 0, 0);
            }
            if (row < NN) {
                *(f32x4*)(P + (size_t)row * 128 + hw * 32 + g * 4)      = acc0;
                *(f32x4*)(P + (size_t)row * 128 + hw * 32 + 16 + g * 4) = acc1;
            }
        }
    } else {
        const short* Wb = WhiBase + 2 * 16384;
        bf16x8 wv[2][4];
#pragma unroll
        for (int dtt = 0; dtt < 2; ++dtt)
#pragma unroll
            for (int kc = 0; kc < 4; ++kc)
                wv[dtt][kc] = pin8(*(const bf16x8*)(Wb + (hw * 32 + dtt * 16 + el) * 128 + kc * 32 + g * 8));

        for (int tile = blockIdx.x; tile < ntiles; tile += gridDim.x) {
            const int row = tile * 16 + el;
            const int rc = row < NN ? row : NN - 1;
            const float* xrow = inV + (size_t)rc * 128;
            f32x4 acc0 = {}, acc1 = {};
#pragma unroll
            for (int kc = 0; kc < 4; ++kc) {
                const int kb = kc * 32 + g * 8;
                f32x4 x0 = *(const f32x4*)(xrow + kb);
                f32x4 x1 = *(const f32x4*)(xrow + kb + 4);
                bf16x8 b;
#pragma unroll
                for (int j = 0; j < 4; ++j) { b[j] = f2bf(x0[j]); b[4 + j] = f2bf(x1[j]); }
                acc0 = __builtin_amdgcn_mfma_f32_16x16x32_bf16(wv[0][kc], b, acc0, 0, 0, 0);
                acc1 = __builtin_amdgcn_mfma_f32_16x16x32_bf16(wv[1][kc], b, acc1, 0, 0, 0);
            }
            if (row < NN) {
                bf16x4 o0, o1;
#pragma unroll
                for (int j = 0; j < 4; ++j) { o0[j] = f2bf(acc0[j]); o1[j] = f2bf(acc1[j]); }
                *(bf16x4*)(Vb + (size_t)row * 128 + hw * 32 + g * 4)      = o0;
                *(bf16x4*)(Vb + (size_t)row * 128 + hw * 32 + 16 + g * 4) = o1;
            }
        }
    }
}

// ---------------- K2a: LDS-staged Ef-GEMM + score + exp (counted-vmcnt barrier) -------
// 8 waves/SIMD occupancy: VGPR budget 64 (fits — R8 compiled to exactly 64), LDS
// 17.4KB x 8 blocks = 139KB < 160KB. Barrier is lgkmcnt(0) + raw s_barrier ONLY —
// global loads stay in flight across it (counted vmcnt at first use).
__global__ __launch_bounds__(256, 8) void edge_score_kernel(
    const int4* __restrict__ pack, const float* __restrict__ efeat,
    const float* __restrict__ Qf, const float* __restrict__ Kf,
    const short* __restrict__ WEhi, const short* __restrict__ WElo,
    float* __restrict__ attn_out, float* __restrict__ attn_csr)
{
    __shared__ short lds_hi[2][16][136];   // [buf][edge][dim]
    __shared__ short lds_lo[2][16][136];

    const int t    = threadIdx.x;
    const int lane = t & 63;
    const int hw   = t >> 6;              // head / wave
    const int el   = lane & 15;
    const int g    = lane >> 4;
    const int se   = t >> 4;              // staging: edge 0..15
    const int sd   = (t & 15) * 8;        // staging: dim
    const int NT   = EN / 16;

    // pinned weight fragments
    bf16x8 wh[2][4], wl[2][4];
#pragma unroll
    for (int dtt = 0; dtt < 2; ++dtt)
#pragma unroll
        for (int kc = 0; kc < 4; ++kc) {
            const int r = hw * 32 + dtt * 16 + el;
            const int c = kc * 32 + g * 8;
            wh[dtt][kc] = pin8(*(const bf16x8*)(WEhi + r * 128 + c));
            wl[dtt][kc] = pin8(*(const bf16x8*)(WElo + r * 128 + c));
        }

    const int dbase = hw * 32 + g * 4;
    int tile = blockIdx.x;
    int4 pk = pack[tile * 16 + el];

    // prologue: stage tile0 -> LDS[0]
    {
        const float* p = efeat + ((size_t)tile * 16 + se) * 128 + sd;
        f32x4 a = *(const f32x4*)p;
        f32x4 b = *(const f32x4*)(p + 4);
        bf16x8 h8, l8;
#pragma unroll
        for (int j = 0; j < 4; ++j) {
            h8[j] = f2bf(a[j]);     l8[j] = f2bf(a[j] - bf2f(h8[j]));
            h8[4 + j] = f2bf(b[j]); l8[4 + j] = f2bf(b[j] - bf2f(h8[4 + j]));
        }
        *(bf16x8*)&lds_hi[0][se][sd] = h8;
        *(bf16x8*)&lds_lo[0][se][sd] = l8;
    }

    int buf = 0;
    while (true) {
        // 1) gathers for current tile (vmcnt; consumed after the MFMA phase)
        const float* qrow = Qf + (size_t)pk.x * 128 + dbase;
        const float* krow = Kf + (size_t)pk.y * 128 + dbase;
        f32x4 q0 = *(const f32x4*)(qrow);
        f32x4 q1 = *(const f32x4*)(qrow + 16);
        f32x4 k0 = *(const f32x4*)(krow);
        f32x4 k1 = *(const f32x4*)(krow + 16);

        // 2) issue next tile's staging loads + pack prefetch (latency hides under MFMA)
        const int next = tile + (int)gridDim.x;
        const bool has_next = next < NT;
        const int tload = has_next ? next : tile;
        const float* np = efeat + ((size_t)tload * 16 + se) * 128 + sd;
        f32x4 ea = *(const f32x4*)np;
        f32x4 eb = *(const f32x4*)(np + 4);
        int4 pkn = pack[tload * 16 + el];

        // barrier: order LDS double-buffer only — do NOT drain vmcnt
        asm volatile("s_waitcnt lgkmcnt(0)" ::: "memory");
        __builtin_amdgcn_s_barrier();
        __builtin_amdgcn_sched_barrier(0);

        // 3) MFMA phase from LDS (lgkmcnt only)
        __builtin_amdgcn_s_setprio(1);
        f32x4 acc0 = {}, acc1 = {};
#pragma unroll
        for (int kc = 0; kc < 4; ++kc) {
            const int kb = kc * 32 + g * 8;
            bf16x8 bh = *(const bf16x8*)&lds_hi[buf][el][kb];
            bf16x8 bl = *(const bf16x8*)&lds_lo[buf][el][kb];
            acc0 = __builtin_amdgcn_mfma_f32_16x16x32_bf16(wh[0][kc], bh, acc0, 0, 0, 0);
            acc0 = __builtin_amdgcn_mfma_f32_16x16x32_bf16(wh[0][kc], bl, acc0, 0, 0, 0);
            acc0 = __builtin_amdgcn_mfma_f32_16x16x32_bf16(wl[0][kc], bh, acc0, 0, 0, 0);
            acc1 = __builtin_amdgcn_mfma_f32_16x16x32_bf16(wh[1][kc], bh, acc1, 0, 0, 0);
            acc1 = __builtin_amdgcn_mfma_f32_16x16x32_bf16(wh[1][kc], bl, acc1, 0, 0, 0);
            acc1 = __builtin_amdgcn_mfma_f32_16x16x32_bf16(wl[1][kc], bh, acc1, 0, 0, 0);
        }
        __builtin_amdgcn_s_setprio(0);

        // 4) combine (first consumer of this iteration's gathers)
        float part = 0.f;
#pragma unroll
        for (int j = 0; j < 4; ++j) {
            part += q0[j] * k0[j] * acc0[j];
            part += q1[j] * k1[j] * acc1[j];
        }
        part += __shfl_xor(part, 16, 64);
        part += __shfl_xor(part, 32, 64);
        float sc = part * 0.17677669529663687f;     // 1/sqrt(32)
        sc = fminf(5.0f, fmaxf(-5.0f, sc));
        const float a = __expf(sc);

        const int edge = tile * 16 + el;
        if (g == 0) {
            attn_out[(size_t)hw * EN + edge] = a;          // coalesced 64B per wave
            attn_csr[(size_t)pk.z * 4 + hw] = a;           // scattered 4B
        }

        if (!has_next) break;

        // 5) convert + write next tile into LDS[buf^1]
        {
            bf16x8 h8, l8;
#pragma unroll
            for (int j = 0; j < 4; ++j) {
                h8[j] = f2bf(ea[j]);     l8[j] = f2bf(ea[j] - bf2f(h8[j]));
                h8[4 + j] = f2bf(eb[j]); l8[4 + j] = f2bf(eb[j] - bf2f(h8[4 + j]));
            }
            *(bf16x8*)&lds_hi[buf ^ 1][se][sd] = h8;
            *(bf16x8*)&lds_lo[buf ^ 1][se][sd] = l8;
        }
        tile = next;
        pk = pkn;
        buf ^= 1;
    }
}

// ---------------- K2b: per-node gather-reduce + W_fc matvec + residual + LN ----------
// 512 threads = 32 nodes/block: one W_fc LDS copy amortized 2x, LDS 51.7KB ->
// 3 blocks x 8 waves = 24 waves/CU (75%) vs previous 37%.
__global__ __launch_bounds__(512) void node_kernel(
    const int* __restrict__ base, const int* __restrict__ tgt_csr,
    const float* __restrict__ attn_csr, const short* __restrict__ Vb,
    const short* __restrict__ Wfcb, const float* __restrict__ inQ,
    const float* __restrict__ gamma, const float* __restrict__ beta,
    float* __restrict__ y)
{
    __shared__ short wlds[128 * 136];   // padded: stride 136 bf16
    __shared__ float alds[32 * 132];    // padded: stride 132 f32

    const int t = threadIdx.x;
    // stage W_fc: thread handles row r=t>>2, cols (t&3)*32..+31
    {
        const int r = t >> 2, colb = (t & 3) * 32;
#pragma unroll
        for (int c = 0; c < 4; ++c) {
            bf16x8 w = *(const bf16x8*)(Wfcb + r * 128 + colb + c * 8);
            *(bf16x8*)(&wlds[r * 136 + colb + c * 8]) = w;
        }
    }

    const int n_l = t >> 4;             // 0..31
    const int el  = t & 15;
    const int node = blockIdx.x * 32 + n_l;

    int b0 = 0, b1 = 0;
    if (node < NN) { b0 = base[node]; b1 = base[node + 1]; }
    float acc[8] = {};
    float csum = 0.f;
    const int h = el >> 2;

    int p = b0;
    for (; p + 8 <= b1; p += 8) {      // unroll x8 for memory-level parallelism
        int   tg[8];
        float aa[8];
        bf16x8 vv[8];
#pragma unroll
        for (int u = 0; u < 8; ++u) tg[u] = tgt_csr[p + u];
#pragma unroll
        for (int u = 0; u < 8; ++u) aa[u] = attn_csr[(size_t)(p + u) * 4 + h];
#pragma unroll
        for (int u = 0; u < 8; ++u) vv[u] = *(const bf16x8*)(Vb + (size_t)tg[u] * 128 + el * 8);
#pragma unroll
        for (int u = 0; u < 8; ++u) {
            csum += aa[u];
#pragma unroll
            for (int j = 0; j < 8; ++j) acc[j] += aa[u] * bf2f(vv[u][j]);
        }
    }
    for (; p < b1; ++p) {
        const int tg = tgt_csr[p];
        const float a = attn_csr[(size_t)p * 4 + h];
        bf16x8 v = *(const bf16x8*)(Vb + (size_t)tg * 128 + el * 8);
        csum += a;
#pragma unroll
        for (int j = 0; j < 8; ++j) acc[j] += a * bf2f(v[j]);
    }

    const float invc = 1.0f / (csum + 1e-8f);
#pragma unroll
    for (int j = 0; j < 8; ++j) alds[n_l * 132 + el * 8 + j] = acc[j] * invc;
    __syncthreads();

    float fc[8] = {};
#pragma unroll 4
    for (int k0 = 0; k0 < 128; k0 += 8) {
        float a8[8];
#pragma unroll
        for (int j = 0; j < 8; ++j) a8[j] = alds[n_l * 132 + k0 + j];
#pragma unroll
        for (int i = 0; i < 8; ++i) {
            const int d = el + 16 * i;
            bf16x8 w = *(const bf16x8*)(&wlds[d * 136 + k0]);
#pragma unroll
            for (int j = 0; j < 8; ++j) fc[i] += a8[j] * bf2f(w[j]);
        }
    }

    if (node < NN) {
        float x[8];
        float s = 0.f, s2 = 0.f;
#pragma unroll
        for (int i = 0; i < 8; ++i) {
            const int d = el + 16 * i;
            x[i] = fc[i] + inQ[(size_t)node * 128 + d];
            s += x[i]; s2 += x[i] * x[i];
        }
        s  += __shfl_xor(s, 1, 64);  s2 += __shfl_xor(s2, 1, 64);
        s  += __shfl_xor(s, 2, 64);  s2 += __shfl_xor(s2, 2, 64);
        s  += __shfl_xor(s, 4, 64);  s2 += __shfl_xor(s2, 4, 64);
        s  += __shfl_xor(s, 8, 64);  s2 += __shfl_xor(s2, 8, 64);
        const float mu = s * (1.0f / 128.0f);
        const float var = s2 * (1.0f / 128.0f) - mu * mu;
        const float rstd = rsqrtf(var + 1e-5f);
#pragma unroll
        for (int i = 0; i < 8; ++i) {
            const int d = el + 16 * i;
            y[(size_t)node * 128 + d] = (x[i] - mu) * rstd * gamma[d] + beta[d];
        }
    }
}

// ---------------- launcher ----------------
extern "C" void kernel_launch(void* const* d_in, const int* in_sizes, int n_in,
                              void* d_out, int out_size, void* d_ws, size_t ws_size,
                              hipStream_t stream) {
    const int*   eidx  = (const int*)d_in[0];
    const float* efeat = (const float*)d_in[1];
    const float* inQ   = (const float*)d_in[2];
    const float* inK   = (const float*)d_in[3];
    const float* inV   = (const float*)d_in[4];
    const float* WQ    = (const float*)d_in[5];
    const float* WK    = (const float*)d_in[6];
    const float* WV    = (const float*)d_in[7];
    const float* WE    = (const float*)d_in[8];
    const float* Wfc   = (const float*)d_in[9];
    const float* gamma = (const float*)d_in[10];
    const float* beta  = (const float*)d_in[11];

    float* y = (float*)d_out;
    float* attn_out = y + (size_t)NN * 128;   // 3,200,000

    // ws layout (bytes): same as R6/R7/R8
    char* ws = (char*)d_ws;
    float* Qf      = (float*)ws;
    float* Kf      = (float*)(ws + 12800000);
    short* Vb      = (short*)(ws + 25600000);
    short* Whi     = (short*)(ws + 32000000);
    short* Wlo     = (short*)(ws + 32163840);
    float* attn_csr= (float*)(ws + 32262144);
    int*   tgt_csr = (int*)  (ws + 38662144);
    int4*  pack    = (int4*) (ws + 40262144);
    int*   deg     = (int*)  (ws + 46662144);
    int*   cnt     = (int*)  (ws + 46762496);
    int*   base    = (int*)  (ws + 46862848);

    hipMemsetAsync(deg, 0, 200704, stream);   // deg + cnt

    convert_hist_kernel<<<512 + (EN + 255) / 256, 256, 0, stream>>>(
        WQ, WK, WV, WE, Wfc, Whi, Wlo, eidx, deg);
    scan_kernel<<<1, 1024, 0, stream>>>(deg, base);
    scatter_kernel<<<(EN + 255) / 256, 256, 0, stream>>>(eidx, base, cnt, pack, tgt_csr);

    dim3 pg(391, 3);
    proj_all_kernel<<<pg, 256, 0, stream>>>(inQ, inK, inV, Whi, Wlo, Qf, Kf, Vb);

    edge_score_kernel<<<2048, 256, 0, stream>>>(pack, efeat, Qf, Kf,
                                                Whi + 3 * 16384, Wlo + 2 * 16384,
                                                attn_out, attn_csr);

    node_kernel<<<(NN + 31) / 32, 512, 0, stream>>>(base, tgt_csr, attn_csr, Vb,
                                                    Whi + 4 * 16384, inQ, gamma, beta, y);
}

// Round 10
// 263.376 us; speedup vs baseline: 1.9573x; 1.9573x over previous
//
#include <hip/hip_runtime.h>
#include <hip/hip_bf16.h>
#include <cstdint>
#include <cstddef>

// Problem constants (B=1)
#define EN 400000   // edges
#define NN 25000    // nodes
// D=128, H=4, DK=DV=32

typedef __attribute__((ext_vector_type(8))) short bf16x8;
typedef __attribute__((ext_vector_type(4))) short bf16x4;
typedef __attribute__((ext_vector_type(4))) float f32x4;

__device__ __forceinline__ short f2bf(float f) {
    unsigned int u = __float_as_uint(f);
    u = (u + 0x7fffu + ((u >> 16) & 1u)) >> 16;   // RNE
    return (short)u;
}
__device__ __forceinline__ float bf2f(short s) {
    return __uint_as_float(((unsigned int)(unsigned short)s) << 16);
}

// Identity ds_bpermute: result is DS-defined, so the compiler cannot rematerialize
// it from the original global load -> weight fragments stay register-resident.
__device__ __forceinline__ bf16x8 pin8(bf16x8 v) {
    union { bf16x8 s; int i[4]; } u; u.s = v;
    const int a = (threadIdx.x & 63) << 2;
#pragma unroll
    for (int k = 0; k < 4; ++k) u.i[k] = __builtin_amdgcn_ds_bpermute(a, u.i[k]);
    return u.s;
}

// ---------------- K0: fused weights->bf16 (hi 5 mats, lo 3 mats) + degree histogram ---
__global__ __launch_bounds__(256) void convert_hist_kernel(
    const float* __restrict__ w0, const float* __restrict__ w1,
    const float* __restrict__ w2, const float* __restrict__ w3,
    const float* __restrict__ w4, short* __restrict__ hi, short* __restrict__ lo,
    const int* __restrict__ eidx, int* __restrict__ deg)
{
    if (blockIdx.x < 512) {
        int i = blockIdx.x * 256 + threadIdx.x;      // 131072 threads
        if (i < 81920) {
            int w = i >> 14, off = i & 16383;
            const float* src = (w == 0) ? w0 : (w == 1) ? w1 : (w == 2) ? w2 : (w == 3) ? w3 : w4;
            hi[i] = f2bf(src[off]);
        } else {
            int j = i - 81920;                       // WQ, WK, WE lo parts
            int m = j >> 14, off = j & 16383;
            const float* src = (m == 0) ? w0 : (m == 1) ? w1 : w3;
            float x = src[off];
            short h = f2bf(x);
            lo[j] = f2bf(x - bf2f(h));
        }
    } else {
        int e = (blockIdx.x - 512) * 256 + threadIdx.x;
        if (e < EN) atomicAdd(&deg[eidx[e]], 1);
    }
}

// ---------------- CSR scan ----------------
__global__ __launch_bounds__(1024) void scan_kernel(
    const int* __restrict__ deg, int* __restrict__ base)
{
    __shared__ int part[1024];
    const int t = threadIdx.x;
    const int CH = 25;                       // 1024*25 = 25600 >= NN
    int loc[CH];
    int s = 0;
#pragma unroll
    for (int i = 0; i < CH; ++i) {
        int idx = t * CH + i;
        loc[i] = s;
        s += (idx < NN) ? deg[idx] : 0;
    }
    part[t] = s;
    __syncthreads();
    for (int d = 1; d < 1024; d <<= 1) {
        int v = (t >= d) ? part[t - d] : 0;
        __syncthreads();
        part[t] += v;
        __syncthreads();
    }
    int off = (t > 0) ? part[t - 1] : 0;
#pragma unroll
    for (int i = 0; i < CH; ++i) {
        int idx = t * CH + i;
        if (idx < NN) base[idx] = off + loc[i];
    }
    if (t == 1023) base[NN] = part[1023];
}

// writes pack[e] = {src, tgt, csr_pos, 0} and tgt_csr[csr_pos] = tgt
__global__ __launch_bounds__(256) void scatter_kernel(
    const int* __restrict__ eidx, const int* __restrict__ base,
    int* __restrict__ cnt, int4* __restrict__ pack, int* __restrict__ tgt_csr)
{
    int e = blockIdx.x * 256 + threadIdx.x;
    if (e < EN) {
        int s = eidx[e];
        int tg = eidx[EN + e];
        int p = base[s] + atomicAdd(&cnt[s], 1);
        pack[e] = make_int4(s, tg, p, 0);
        tgt_csr[p] = tg;
    }
}

// ---------------- K1: fused head-split projections (Q,K split-precision; V bf16) ------
// blockIdx.y: 0=Q, 1=K, 2=V. Wave hw = head hw: outdims [32hw, 32hw+32).
__global__ __launch_bounds__(256, 4) void proj_all_kernel(
    const float* __restrict__ inQ, const float* __restrict__ inK,
    const float* __restrict__ inV,
    const short* __restrict__ WhiBase, const short* __restrict__ WloBase,
    float* __restrict__ Qf, float* __restrict__ Kf, short* __restrict__ Vb)
{
    const int mode = blockIdx.y;
    const int lane = threadIdx.x & 63;
    const int hw = threadIdx.x >> 6;          // head / wave
    const int el = lane & 15;
    const int g  = lane >> 4;
    const int ntiles = (NN + 15) >> 4;

    if (mode < 2) {
        const float* X = mode ? inK : inQ;
        const short* Whi = WhiBase + mode * 16384;
        const short* Wlo = WloBase + mode * 16384;
        float* P = mode ? Kf : Qf;

        bf16x8 wh[2][4], wl[2][4];
#pragma unroll
        for (int dtt = 0; dtt < 2; ++dtt)
#pragma unroll
            for (int kc = 0; kc < 4; ++kc) {
                const int r = hw * 32 + dtt * 16 + el;
                const int c = kc * 32 + g * 8;
                wh[dtt][kc] = pin8(*(const bf16x8*)(Whi + r * 128 + c));
                wl[dtt][kc] = pin8(*(const bf16x8*)(Wlo + r * 128 + c));
            }

        for (int tile = blockIdx.x; tile < ntiles; tile += gridDim.x) {
            const int row = tile * 16 + el;
            const int rc = row < NN ? row : NN - 1;
            const float* xrow = X + (size_t)rc * 128;
            f32x4 acc0 = {}, acc1 = {};
#pragma unroll
            for (int kc = 0; kc < 4; ++kc) {
                const int kb = kc * 32 + g * 8;
                f32x4 x0 = *(const f32x4*)(xrow + kb);
                f32x4 x1 = *(const f32x4*)(xrow + kb + 4);
                bf16x8 bh, bl;
#pragma unroll
                for (int j = 0; j < 4; ++j) {
                    bh[j] = f2bf(x0[j]); bl[j] = f2bf(x0[j] - bf2f(bh[j]));
                    bh[4 + j] = f2bf(x1[j]); bl[4 + j] = f2bf(x1[j] - bf2f(bh[4 + j]));
                }
                acc0 = __builtin_amdgcn_mfma_f32_16x16x32_bf16(wh[0][kc], bh, acc0, 0, 0, 0);
                acc0 = __builtin_amdgcn_mfma_f32_16x16x32_bf16(wh[0][kc], bl, acc0, 0, 0, 0);
                acc0 = __builtin_amdgcn_mfma_f32_16x16x32_bf16(wl[0][kc], bh, acc0, 0, 0, 0);
                acc1 = __builtin_amdgcn_mfma_f32_16x16x32_bf16(wh[1][kc], bh, acc1, 0, 0, 0);
                acc1 = __builtin_amdgcn_mfma_f32_16x16x32_bf16(wh[1][kc], bl, acc1, 0, 0, 0);
                acc1 = __builtin_amdgcn_mfma_f32_16x16x32_bf16(wl[1][kc], bh, acc1, 0, 0, 0);
            }
            if (row < NN) {
                *(f32x4*)(P + (size_t)row * 128 + hw * 32 + g * 4)      = acc0;
                *(f32x4*)(P + (size_t)row * 128 + hw * 32 + 16 + g * 4) = acc1;
            }
        }
    } else {
        const short* Wb = WhiBase + 2 * 16384;
        bf16x8 wv[2][4];
#pragma unroll
        for (int dtt = 0; dtt < 2; ++dtt)
#pragma unroll
            for (int kc = 0; kc < 4; ++kc)
                wv[dtt][kc] = pin8(*(const bf16x8*)(Wb + (hw * 32 + dtt * 16 + el) * 128 + kc * 32 + g * 8));

        for (int tile = blockIdx.x; tile < ntiles; tile += gridDim.x) {
            const int row = tile * 16 + el;
            const int rc = row < NN ? row : NN - 1;
            const float* xrow = inV + (size_t)rc * 128;
            f32x4 acc0 = {}, acc1 = {};
#pragma unroll
            for (int kc = 0; kc < 4; ++kc) {
                const int kb = kc * 32 + g * 8;
                f32x4 x0 = *(const f32x4*)(xrow + kb);
                f32x4 x1 = *(const f32x4*)(xrow + kb + 4);
                bf16x8 b;
#pragma unroll
                for (int j = 0; j < 4; ++j) { b[j] = f2bf(x0[j]); b[4 + j] = f2bf(x1[j]); }
                acc0 = __builtin_amdgcn_mfma_f32_16x16x32_bf16(wv[0][kc], b, acc0, 0, 0, 0);
                acc1 = __builtin_amdgcn_mfma_f32_16x16x32_bf16(wv[1][kc], b, acc1, 0, 0, 0);
            }
            if (row < NN) {
                bf16x4 o0, o1;
#pragma unroll
                for (int j = 0; j < 4; ++j) { o0[j] = f2bf(acc0[j]); o1[j] = f2bf(acc1[j]); }
                *(bf16x4*)(Vb + (size_t)row * 128 + hw * 32 + g * 4)      = o0;
                *(bf16x4*)(Vb + (size_t)row * 128 + hw * 32 + 16 + g * 4) = o1;
            }
        }
    }
}

// ---------------- K2a: LDS-staged Ef-GEMM + score + exp (counted-vmcnt barrier) -------
// bounds(256,4): compiles to 64 VGPR (R8-proven) which ALREADY permits 8 waves/SIMD in
// HW; grid 2048 = 8 blocks/CU co-resident (LDS 8x17.4KB=139KB<160KB). Do NOT force
// min-waves=8 — that drops the allocator to 32 VGPR and spills everything (R9).
__global__ __launch_bounds__(256, 4) void edge_score_kernel(
    const int4* __restrict__ pack, const float* __restrict__ efeat,
    const float* __restrict__ Qf, const float* __restrict__ Kf,
    const short* __restrict__ WEhi, const short* __restrict__ WElo,
    float* __restrict__ attn_out, float* __restrict__ attn_csr)
{
    __shared__ short lds_hi[2][16][136];   // [buf][edge][dim]
    __shared__ short lds_lo[2][16][136];

    const int t    = threadIdx.x;
    const int lane = t & 63;
    const int hw   = t >> 6;              // head / wave
    const int el   = lane & 15;
    const int g    = lane >> 4;
    const int se   = t >> 4;              // staging: edge 0..15
    const int sd   = (t & 15) * 8;        // staging: dim
    const int NT   = EN / 16;

    // pinned weight fragments
    bf16x8 wh[2][4], wl[2][4];
#pragma unroll
    for (int dtt = 0; dtt < 2; ++dtt)
#pragma unroll
        for (int kc = 0; kc < 4; ++kc) {
            const int r = hw * 32 + dtt * 16 + el;
            const int c = kc * 32 + g * 8;
            wh[dtt][kc] = pin8(*(const bf16x8*)(WEhi + r * 128 + c));
            wl[dtt][kc] = pin8(*(const bf16x8*)(WElo + r * 128 + c));
        }

    const int dbase = hw * 32 + g * 4;
    int tile = blockIdx.x;
    int4 pk = pack[tile * 16 + el];

    // prologue: stage tile0 -> LDS[0]
    {
        const float* p = efeat + ((size_t)tile * 16 + se) * 128 + sd;
        f32x4 a = *(const f32x4*)p;
        f32x4 b = *(const f32x4*)(p + 4);
        bf16x8 h8, l8;
#pragma unroll
        for (int j = 0; j < 4; ++j) {
            h8[j] = f2bf(a[j]);     l8[j] = f2bf(a[j] - bf2f(h8[j]));
            h8[4 + j] = f2bf(b[j]); l8[4 + j] = f2bf(b[j] - bf2f(h8[4 + j]));
        }
        *(bf16x8*)&lds_hi[0][se][sd] = h8;
        *(bf16x8*)&lds_lo[0][se][sd] = l8;
    }

    int buf = 0;
    while (true) {
        // 1) gathers for current tile (vmcnt; consumed after the MFMA phase)
        const float* qrow = Qf + (size_t)pk.x * 128 + dbase;
        const float* krow = Kf + (size_t)pk.y * 128 + dbase;
        f32x4 q0 = *(const f32x4*)(qrow);
        f32x4 q1 = *(const f32x4*)(qrow + 16);
        f32x4 k0 = *(const f32x4*)(krow);
        f32x4 k1 = *(const f32x4*)(krow + 16);

        // 2) issue next tile's staging loads + pack prefetch (latency hides under MFMA)
        const int next = tile + (int)gridDim.x;
        const bool has_next = next < NT;
        const int tload = has_next ? next : tile;
        const float* np = efeat + ((size_t)tload * 16 + se) * 128 + sd;
        f32x4 ea = *(const f32x4*)np;
        f32x4 eb = *(const f32x4*)(np + 4);
        int4 pkn = pack[tload * 16 + el];

        // barrier: order LDS double-buffer only — do NOT drain vmcnt
        asm volatile("s_waitcnt lgkmcnt(0)" ::: "memory");
        __builtin_amdgcn_s_barrier();
        __builtin_amdgcn_sched_barrier(0);

        // 3) MFMA phase from LDS (lgkmcnt only)
        __builtin_amdgcn_s_setprio(1);
        f32x4 acc0 = {}, acc1 = {};
#pragma unroll
        for (int kc = 0; kc < 4; ++kc) {
            const int kb = kc * 32 + g * 8;
            bf16x8 bh = *(const bf16x8*)&lds_hi[buf][el][kb];
            bf16x8 bl = *(const bf16x8*)&lds_lo[buf][el][kb];
            acc0 = __builtin_amdgcn_mfma_f32_16x16x32_bf16(wh[0][kc], bh, acc0, 0, 0, 0);
            acc0 = __builtin_amdgcn_mfma_f32_16x16x32_bf16(wh[0][kc], bl, acc0, 0, 0, 0);
            acc0 = __builtin_amdgcn_mfma_f32_16x16x32_bf16(wl[0][kc], bh, acc0, 0, 0, 0);
            acc1 = __builtin_amdgcn_mfma_f32_16x16x32_bf16(wh[1][kc], bh, acc1, 0, 0, 0);
            acc1 = __builtin_amdgcn_mfma_f32_16x16x32_bf16(wh[1][kc], bl, acc1, 0, 0, 0);
            acc1 = __builtin_amdgcn_mfma_f32_16x16x32_bf16(wl[1][kc], bh, acc1, 0, 0, 0);
        }
        __builtin_amdgcn_s_setprio(0);

        // 4) combine (first consumer of this iteration's gathers)
        float part = 0.f;
#pragma unroll
        for (int j = 0; j < 4; ++j) {
            part += q0[j] * k0[j] * acc0[j];
            part += q1[j] * k1[j] * acc1[j];
        }
        part += __shfl_xor(part, 16, 64);
        part += __shfl_xor(part, 32, 64);
        float sc = part * 0.17677669529663687f;     // 1/sqrt(32)
        sc = fminf(5.0f, fmaxf(-5.0f, sc));
        const float a = __expf(sc);

        const int edge = tile * 16 + el;
        if (g == 0) {
            attn_out[(size_t)hw * EN + edge] = a;          // coalesced 64B per wave
            attn_csr[(size_t)pk.z * 4 + hw] = a;           // scattered 4B
        }

        if (!has_next) break;

        // 5) convert + write next tile into LDS[buf^1]
        {
            bf16x8 h8, l8;
#pragma unroll
            for (int j = 0; j < 4; ++j) {
                h8[j] = f2bf(ea[j]);     l8[j] = f2bf(ea[j] - bf2f(h8[j]));
                h8[4 + j] = f2bf(eb[j]); l8[4 + j] = f2bf(eb[j] - bf2f(h8[4 + j]));
            }
            *(bf16x8*)&lds_hi[buf ^ 1][se][sd] = h8;
            *(bf16x8*)&lds_lo[buf ^ 1][se][sd] = l8;
        }
        tile = next;
        pk = pkn;
        buf ^= 1;
    }
}

// ---------------- K2b: per-node gather-reduce + W_fc matvec + residual + LN ----------
// 512 threads = 32 nodes/block: one W_fc LDS copy amortized 2x.
__global__ __launch_bounds__(512) void node_kernel(
    const int* __restrict__ base, const int* __restrict__ tgt_csr,
    const float* __restrict__ attn_csr, const short* __restrict__ Vb,
    const short* __restrict__ Wfcb, const float* __restrict__ inQ,
    const float* __restrict__ gamma, const float* __restrict__ beta,
    float* __restrict__ y)
{
    __shared__ short wlds[128 * 136];   // padded: stride 136 bf16
    __shared__ float alds[32 * 132];    // padded: stride 132 f32

    const int t = threadIdx.x;
    // stage W_fc: thread handles row r=t>>2, cols (t&3)*32..+31
    {
        const int r = t >> 2, colb = (t & 3) * 32;
#pragma unroll
        for (int c = 0; c < 4; ++c) {
            bf16x8 w = *(const bf16x8*)(Wfcb + r * 128 + colb + c * 8);
            *(bf16x8*)(&wlds[r * 136 + colb + c * 8]) = w;
        }
    }

    const int n_l = t >> 4;             // 0..31
    const int el  = t & 15;
    const int node = blockIdx.x * 32 + n_l;

    int b0 = 0, b1 = 0;
    if (node < NN) { b0 = base[node]; b1 = base[node + 1]; }
    float acc[8] = {};
    float csum = 0.f;
    const int h = el >> 2;

    int p = b0;
    for (; p + 8 <= b1; p += 8) {      // unroll x8 for memory-level parallelism
        int   tg[8];
        float aa[8];
        bf16x8 vv[8];
#pragma unroll
        for (int u = 0; u < 8; ++u) tg[u] = tgt_csr[p + u];
#pragma unroll
        for (int u = 0; u < 8; ++u) aa[u] = attn_csr[(size_t)(p + u) * 4 + h];
#pragma unroll
        for (int u = 0; u < 8; ++u) vv[u] = *(const bf16x8*)(Vb + (size_t)tg[u] * 128 + el * 8);
#pragma unroll
        for (int u = 0; u < 8; ++u) {
            csum += aa[u];
#pragma unroll
            for (int j = 0; j < 8; ++j) acc[j] += aa[u] * bf2f(vv[u][j]);
        }
    }
    for (; p < b1; ++p) {
        const int tg = tgt_csr[p];
        const float a = attn_csr[(size_t)p * 4 + h];
        bf16x8 v = *(const bf16x8*)(Vb + (size_t)tg * 128 + el * 8);
        csum += a;
#pragma unroll
        for (int j = 0; j < 8; ++j) acc[j] += a * bf2f(v[j]);
    }

    const float invc = 1.0f / (csum + 1e-8f);
#pragma unroll
    for (int j = 0; j < 8; ++j) alds[n_l * 132 + el * 8 + j] = acc[j] * invc;
    __syncthreads();

    float fc[8] = {};
#pragma unroll 4
    for (int k0 = 0; k0 < 128; k0 += 8) {
        float a8[8];
#pragma unroll
        for (int j = 0; j < 8; ++j) a8[j] = alds[n_l * 132 + k0 + j];
#pragma unroll
        for (int i = 0; i < 8; ++i) {
            const int d = el + 16 * i;
            bf16x8 w = *(const bf16x8*)(&wlds[d * 136 + k0]);
#pragma unroll
            for (int j = 0; j < 8; ++j) fc[i] += a8[j] * bf2f(w[j]);
        }
    }

    if (node < NN) {
        float x[8];
        float s = 0.f, s2 = 0.f;
#pragma unroll
        for (int i = 0; i < 8; ++i) {
            const int d = el + 16 * i;
            x[i] = fc[i] + inQ[(size_t)node * 128 + d];
            s += x[i]; s2 += x[i] * x[i];
        }
        s  += __shfl_xor(s, 1, 64);  s2 += __shfl_xor(s2, 1, 64);
        s  += __shfl_xor(s, 2, 64);  s2 += __shfl_xor(s2, 2, 64);
        s  += __shfl_xor(s, 4, 64);  s2 += __shfl_xor(s2, 4, 64);
        s  += __shfl_xor(s, 8, 64);  s2 += __shfl_xor(s2, 8, 64);
        const float mu = s * (1.0f / 128.0f);
        const float var = s2 * (1.0f / 128.0f) - mu * mu;
        const float rstd = rsqrtf(var + 1e-5f);
#pragma unroll
        for (int i = 0; i < 8; ++i) {
            const int d = el + 16 * i;
            y[(size_t)node * 128 + d] = (x[i] - mu) * rstd * gamma[d] + beta[d];
        }
    }
}

// ---------------- launcher ----------------
extern "C" void kernel_launch(void* const* d_in, const int* in_sizes, int n_in,
                              void* d_out, int out_size, void* d_ws, size_t ws_size,
                              hipStream_t stream) {
    const int*   eidx  = (const int*)d_in[0];
    const float* efeat = (const float*)d_in[1];
    const float* inQ   = (const float*)d_in[2];
    const float* inK   = (const float*)d_in[3];
    const float* inV   = (const float*)d_in[4];
    const float* WQ    = (const float*)d_in[5];
    const float* WK    = (const float*)d_in[6];
    const float* WV    = (const float*)d_in[7];
    const float* WE    = (const float*)d_in[8];
    const float* Wfc   = (const float*)d_in[9];
    const float* gamma = (const float*)d_in[10];
    const float* beta  = (const float*)d_in[11];

    float* y = (float*)d_out;
    float* attn_out = y + (size_t)NN * 128;   // 3,200,000

    // ws layout (bytes): same as R6-R9
    char* ws = (char*)d_ws;
    float* Qf      = (float*)ws;
    float* Kf      = (float*)(ws + 12800000);
    short* Vb      = (short*)(ws + 25600000);
    short* Whi     = (short*)(ws + 32000000);
    short* Wlo     = (short*)(ws + 32163840);
    float* attn_csr= (float*)(ws + 32262144);
    int*   tgt_csr = (int*)  (ws + 38662144);
    int4*  pack    = (int4*) (ws + 40262144);
    int*   deg     = (int*)  (ws + 46662144);
    int*   cnt     = (int*)  (ws + 46762496);
    int*   base    = (int*)  (ws + 46862848);

    hipMemsetAsync(deg, 0, 200704, stream);   // deg + cnt

    convert_hist_kernel<<<512 + (EN + 255) / 256, 256, 0, stream>>>(
        WQ, WK, WV, WE, Wfc, Whi, Wlo, eidx, deg);
    scan_kernel<<<1, 1024, 0, stream>>>(deg, base);
    scatter_kernel<<<(EN + 255) / 256, 256, 0, stream>>>(eidx, base, cnt, pack, tgt_csr);

    dim3 pg(391, 3);
    proj_all_kernel<<<pg, 256, 0, stream>>>(inQ, inK, inV, Whi, Wlo, Qf, Kf, Vb);

    edge_score_kernel<<<2048, 256, 0, stream>>>(pack, efeat, Qf, Kf,
                                                Whi + 3 * 16384, Wlo + 2 * 16384,
                                                attn_out, attn_csr);

    node_kernel<<<(NN + 31) / 32, 512, 0, stream>>>(base, tgt_csr, attn_csr, Vb,
                                                    Whi + 4 * 16384, inQ, gamma, beta, y);
}

// Round 11
// 258.548 us; speedup vs baseline: 1.9939x; 1.0187x over previous
//
#include <hip/hip_runtime.h>
#include <hip/hip_bf16.h>
#include <cstdint>
#include <cstddef>

// Problem constants (B=1)
#define EN 400000   // edges
#define NN 25000    // nodes
// D=128, H=4, DK=DV=32

typedef __attribute__((ext_vector_type(8))) short bf16x8;
typedef __attribute__((ext_vector_type(4))) short bf16x4;
typedef __attribute__((ext_vector_type(4))) float f32x4;

__device__ __forceinline__ short f2bf(float f) {
    unsigned int u = __float_as_uint(f);
    u = (u + 0x7fffu + ((u >> 16) & 1u)) >> 16;   // RNE
    return (short)u;
}
__device__ __forceinline__ float bf2f(short s) {
    return __uint_as_float(((unsigned int)(unsigned short)s) << 16);
}

// Identity ds_bpermute: result is DS-defined, so the compiler cannot rematerialize
// it from the original global load -> weight fragments stay register-resident.
__device__ __forceinline__ bf16x8 pin8(bf16x8 v) {
    union { bf16x8 s; int i[4]; } u; u.s = v;
    const int a = (threadIdx.x & 63) << 2;
#pragma unroll
    for (int k = 0; k < 4; ++k) u.i[k] = __builtin_amdgcn_ds_bpermute(a, u.i[k]);
    return u.s;
}

// ---------------- K0: fused weights->bf16 (hi 5 mats, lo 3 mats) + degree histogram ---
__global__ __launch_bounds__(256) void convert_hist_kernel(
    const float* __restrict__ w0, const float* __restrict__ w1,
    const float* __restrict__ w2, const float* __restrict__ w3,
    const float* __restrict__ w4, short* __restrict__ hi, short* __restrict__ lo,
    const int* __restrict__ eidx, int* __restrict__ deg)
{
    if (blockIdx.x < 512) {
        int i = blockIdx.x * 256 + threadIdx.x;      // 131072 threads
        if (i < 81920) {
            int w = i >> 14, off = i & 16383;
            const float* src = (w == 0) ? w0 : (w == 1) ? w1 : (w == 2) ? w2 : (w == 3) ? w3 : w4;
            hi[i] = f2bf(src[off]);
        } else {
            int j = i - 81920;                       // WQ, WK, WE lo parts
            int m = j >> 14, off = j & 16383;
            const float* src = (m == 0) ? w0 : (m == 1) ? w1 : w3;
            float x = src[off];
            short h = f2bf(x);
            lo[j] = f2bf(x - bf2f(h));
        }
    } else {
        int e = (blockIdx.x - 512) * 256 + threadIdx.x;
        if (e < EN) atomicAdd(&deg[eidx[e]], 1);
    }
}

// ---------------- CSR scan ----------------
__global__ __launch_bounds__(1024) void scan_kernel(
    const int* __restrict__ deg, int* __restrict__ base)
{
    __shared__ int part[1024];
    const int t = threadIdx.x;
    const int CH = 25;                       // 1024*25 = 25600 >= NN
    int loc[CH];
    int s = 0;
#pragma unroll
    for (int i = 0; i < CH; ++i) {
        int idx = t * CH + i;
        loc[i] = s;
        s += (idx < NN) ? deg[idx] : 0;
    }
    part[t] = s;
    __syncthreads();
    for (int d = 1; d < 1024; d <<= 1) {
        int v = (t >= d) ? part[t - d] : 0;
        __syncthreads();
        part[t] += v;
        __syncthreads();
    }
    int off = (t > 0) ? part[t - 1] : 0;
#pragma unroll
    for (int i = 0; i < CH; ++i) {
        int idx = t * CH + i;
        if (idx < NN) base[idx] = off + loc[i];
    }
    if (t == 1023) base[NN] = part[1023];
}

// writes pack[e] = {src, tgt, csr_pos, 0} and tgt_csr[csr_pos] = tgt
__global__ __launch_bounds__(256) void scatter_kernel(
    const int* __restrict__ eidx, const int* __restrict__ base,
    int* __restrict__ cnt, int4* __restrict__ pack, int* __restrict__ tgt_csr)
{
    int e = blockIdx.x * 256 + threadIdx.x;
    if (e < EN) {
        int s = eidx[e];
        int tg = eidx[EN + e];
        int p = base[s] + atomicAdd(&cnt[s], 1);
        pack[e] = make_int4(s, tg, p, 0);
        tgt_csr[p] = tg;
    }
}

// ---------------- K1: fused head-split projections (Q,K split-precision; V bf16) ------
// blockIdx.y: 0=Q, 1=K, 2=V. Wave hw = head hw: outdims [32hw, 32hw+32).
__global__ __launch_bounds__(256, 4) void proj_all_kernel(
    const float* __restrict__ inQ, const float* __restrict__ inK,
    const float* __restrict__ inV,
    const short* __restrict__ WhiBase, const short* __restrict__ WloBase,
    float* __restrict__ Qf, float* __restrict__ Kf, short* __restrict__ Vb)
{
    const int mode = blockIdx.y;
    const int lane = threadIdx.x & 63;
    const int hw = threadIdx.x >> 6;          // head / wave
    const int el = lane & 15;
    const int g  = lane >> 4;
    const int ntiles = (NN + 15) >> 4;

    if (mode < 2) {
        const float* X = mode ? inK : inQ;
        const short* Whi = WhiBase + mode * 16384;
        const short* Wlo = WloBase + mode * 16384;
        float* P = mode ? Kf : Qf;

        bf16x8 wh[2][4], wl[2][4];
#pragma unroll
        for (int dtt = 0; dtt < 2; ++dtt)
#pragma unroll
            for (int kc = 0; kc < 4; ++kc) {
                const int r = hw * 32 + dtt * 16 + el;
                const int c = kc * 32 + g * 8;
                wh[dtt][kc] = pin8(*(const bf16x8*)(Whi + r * 128 + c));
                wl[dtt][kc] = pin8(*(const bf16x8*)(Wlo + r * 128 + c));
            }

        for (int tile = blockIdx.x; tile < ntiles; tile += gridDim.x) {
            const int row = tile * 16 + el;
            const int rc = row < NN ? row : NN - 1;
            const float* xrow = X + (size_t)rc * 128;
            f32x4 acc0 = {}, acc1 = {};
#pragma unroll
            for (int kc = 0; kc < 4; ++kc) {
                const int kb = kc * 32 + g * 8;
                f32x4 x0 = *(const f32x4*)(xrow + kb);
                f32x4 x1 = *(const f32x4*)(xrow + kb + 4);
                bf16x8 bh, bl;
#pragma unroll
                for (int j = 0; j < 4; ++j) {
                    bh[j] = f2bf(x0[j]); bl[j] = f2bf(x0[j] - bf2f(bh[j]));
                    bh[4 + j] = f2bf(x1[j]); bl[4 + j] = f2bf(x1[j] - bf2f(bh[4 + j]));
                }
                acc0 = __builtin_amdgcn_mfma_f32_16x16x32_bf16(wh[0][kc], bh, acc0, 0, 0, 0);
                acc0 = __builtin_amdgcn_mfma_f32_16x16x32_bf16(wh[0][kc], bl, acc0, 0, 0, 0);
                acc0 = __builtin_amdgcn_mfma_f32_16x16x32_bf16(wl[0][kc], bh, acc0, 0, 0, 0);
                acc1 = __builtin_amdgcn_mfma_f32_16x16x32_bf16(wh[1][kc], bh, acc1, 0, 0, 0);
                acc1 = __builtin_amdgcn_mfma_f32_16x16x32_bf16(wh[1][kc], bl, acc1, 0, 0, 0);
                acc1 = __builtin_amdgcn_mfma_f32_16x16x32_bf16(wl[1][kc], bh, acc1, 0, 0, 0);
            }
            if (row < NN) {
                *(f32x4*)(P + (size_t)row * 128 + hw * 32 + g * 4)      = acc0;
                *(f32x4*)(P + (size_t)row * 128 + hw * 32 + 16 + g * 4) = acc1;
            }
        }
    } else {
        const short* Wb = WhiBase + 2 * 16384;
        bf16x8 wv[2][4];
#pragma unroll
        for (int dtt = 0; dtt < 2; ++dtt)
#pragma unroll
            for (int kc = 0; kc < 4; ++kc)
                wv[dtt][kc] = pin8(*(const bf16x8*)(Wb + (hw * 32 + dtt * 16 + el) * 128 + kc * 32 + g * 8));

        for (int tile = blockIdx.x; tile < ntiles; tile += gridDim.x) {
            const int row = tile * 16 + el;
            const int rc = row < NN ? row : NN - 1;
            const float* xrow = inV + (size_t)rc * 128;
            f32x4 acc0 = {}, acc1 = {};
#pragma unroll
            for (int kc = 0; kc < 4; ++kc) {
                const int kb = kc * 32 + g * 8;
                f32x4 x0 = *(const f32x4*)(xrow + kb);
                f32x4 x1 = *(const f32x4*)(xrow + kb + 4);
                bf16x8 b;
#pragma unroll
                for (int j = 0; j < 4; ++j) { b[j] = f2bf(x0[j]); b[4 + j] = f2bf(x1[j]); }
                acc0 = __builtin_amdgcn_mfma_f32_16x16x32_bf16(wv[0][kc], b, acc0, 0, 0, 0);
                acc1 = __builtin_amdgcn_mfma_f32_16x16x32_bf16(wv[1][kc], b, acc1, 0, 0, 0);
            }
            if (row < NN) {
                bf16x4 o0, o1;
#pragma unroll
                for (int j = 0; j < 4; ++j) { o0[j] = f2bf(acc0[j]); o1[j] = f2bf(acc1[j]); }
                *(bf16x4*)(Vb + (size_t)row * 128 + hw * 32 + g * 4)      = o0;
                *(bf16x4*)(Vb + (size_t)row * 128 + hw * 32 + 16 + g * 4) = o1;
            }
        }
    }
}

// ---------------- K2a: LDS-staged Ef-GEMM + score + exp, gathers pipelined 1 iter -----
// Q/K gathers for tile i+1 are issued during iteration i (addresses from the pack
// prefetch chain), so combine(i) consumes loads issued a FULL iteration earlier —
// no vmcnt stall. bounds(256,3): reg budget ~170 fits 64 AGPR weights + double-
// buffered gather state. Do NOT use (256,8): 32-VGPR budget spills everything (R9);
// (256,4)=128 budget is exactly consumed with no room for pipelining (R10).
__global__ __launch_bounds__(256, 3) void edge_score_kernel(
    const int4* __restrict__ pack, const float* __restrict__ efeat,
    const float* __restrict__ Qf, const float* __restrict__ Kf,
    const short* __restrict__ WEhi, const short* __restrict__ WElo,
    float* __restrict__ attn_out, float* __restrict__ attn_csr)
{
    __shared__ short lds_hi[2][16][136];   // [buf][edge][dim]
    __shared__ short lds_lo[2][16][136];

    const int t    = threadIdx.x;
    const int lane = t & 63;
    const int hw   = t >> 6;              // head / wave
    const int el   = lane & 15;
    const int g    = lane >> 4;
    const int se   = t >> 4;              // staging: edge 0..15
    const int sd   = (t & 15) * 8;        // staging: dim
    const int NT   = EN / 16;

    // pinned weight fragments (AGPR side of the unified file)
    bf16x8 wh[2][4], wl[2][4];
#pragma unroll
    for (int dtt = 0; dtt < 2; ++dtt)
#pragma unroll
        for (int kc = 0; kc < 4; ++kc) {
            const int r = hw * 32 + dtt * 16 + el;
            const int c = kc * 32 + g * 8;
            wh[dtt][kc] = pin8(*(const bf16x8*)(WEhi + r * 128 + c));
            wl[dtt][kc] = pin8(*(const bf16x8*)(WElo + r * 128 + c));
        }

    const int dbase = hw * 32 + g * 4;
    int tile = blockIdx.x;
    int4 pk = pack[tile * 16 + el];

    // prologue: gathers for tile0 + pack prefetch for tile1 + stage tile0 -> LDS[0]
    f32x4 qc0, qc1, kc0, kc1;
    {
        const float* qrow = Qf + (size_t)pk.x * 128 + dbase;
        const float* krow = Kf + (size_t)pk.y * 128 + dbase;
        qc0 = *(const f32x4*)(qrow);
        qc1 = *(const f32x4*)(qrow + 16);
        kc0 = *(const f32x4*)(krow);
        kc1 = *(const f32x4*)(krow + 16);
    }
    int n1 = tile + (int)gridDim.x;
    int4 pkn = pack[(n1 < NT ? n1 : tile) * 16 + el];
    {
        const float* p = efeat + ((size_t)tile * 16 + se) * 128 + sd;
        f32x4 a = *(const f32x4*)p;
        f32x4 b = *(const f32x4*)(p + 4);
        bf16x8 h8, l8;
#pragma unroll
        for (int j = 0; j < 4; ++j) {
            h8[j] = f2bf(a[j]);     l8[j] = f2bf(a[j] - bf2f(h8[j]));
            h8[4 + j] = f2bf(b[j]); l8[4 + j] = f2bf(b[j] - bf2f(h8[4 + j]));
        }
        *(bf16x8*)&lds_hi[0][se][sd] = h8;
        *(bf16x8*)&lds_lo[0][se][sd] = l8;
    }

    int buf = 0;
    while (true) {
        const int next = tile + (int)gridDim.x;
        const bool has_next = next < NT;
        const int tload = has_next ? next : tile;

        // A) gathers for NEXT tile (addresses = pkn, prefetched last iteration)
        const int4 pkN = pkn;
        const float* qrowN = Qf + (size_t)pkN.x * 128 + dbase;
        const float* krowN = Kf + (size_t)pkN.y * 128 + dbase;
        f32x4 qn0 = *(const f32x4*)(qrowN);
        f32x4 qn1 = *(const f32x4*)(qrowN + 16);
        f32x4 kn0 = *(const f32x4*)(krowN);
        f32x4 kn1 = *(const f32x4*)(krowN + 16);

        // B) staging loads for NEXT tile + pack prefetch for tile+2
        const float* np = efeat + ((size_t)tload * 16 + se) * 128 + sd;
        f32x4 ea = *(const f32x4*)np;
        f32x4 eb = *(const f32x4*)(np + 4);
        int n2 = next + (int)gridDim.x;
        int4 pkn2 = pack[(n2 < NT ? n2 : tile) * 16 + el];

        // C) barrier: order LDS double-buffer only — do NOT drain vmcnt
        asm volatile("s_waitcnt lgkmcnt(0)" ::: "memory");
        __builtin_amdgcn_s_barrier();
        __builtin_amdgcn_sched_barrier(0);

        // D) MFMA phase from LDS (lgkmcnt only)
        __builtin_amdgcn_s_setprio(1);
        f32x4 acc0 = {}, acc1 = {};
#pragma unroll
        for (int kc = 0; kc < 4; ++kc) {
            const int kb = kc * 32 + g * 8;
            bf16x8 bh = *(const bf16x8*)&lds_hi[buf][el][kb];
            bf16x8 bl = *(const bf16x8*)&lds_lo[buf][el][kb];
            acc0 = __builtin_amdgcn_mfma_f32_16x16x32_bf16(wh[0][kc], bh, acc0, 0, 0, 0);
            acc0 = __builtin_amdgcn_mfma_f32_16x16x32_bf16(wh[0][kc], bl, acc0, 0, 0, 0);
            acc0 = __builtin_amdgcn_mfma_f32_16x16x32_bf16(wl[0][kc], bh, acc0, 0, 0, 0);
            acc1 = __builtin_amdgcn_mfma_f32_16x16x32_bf16(wh[1][kc], bh, acc1, 0, 0, 0);
            acc1 = __builtin_amdgcn_mfma_f32_16x16x32_bf16(wh[1][kc], bl, acc1, 0, 0, 0);
            acc1 = __builtin_amdgcn_mfma_f32_16x16x32_bf16(wl[1][kc], bh, acc1, 0, 0, 0);
        }
        __builtin_amdgcn_s_setprio(0);

        // E) combine with CURRENT gathers (issued one full iteration ago — no stall)
        float part = 0.f;
#pragma unroll
        for (int j = 0; j < 4; ++j) {
            part += qc0[j] * kc0[j] * acc0[j];
            part += qc1[j] * kc1[j] * acc1[j];
        }
        part += __shfl_xor(part, 16, 64);
        part += __shfl_xor(part, 32, 64);
        float sc = part * 0.17677669529663687f;     // 1/sqrt(32)
        sc = fminf(5.0f, fmaxf(-5.0f, sc));
        const float a = __expf(sc);

        const int edge = tile * 16 + el;
        if (g == 0) {
            attn_out[(size_t)hw * EN + edge] = a;          // coalesced 64B per wave
            attn_csr[(size_t)pk.z * 4 + hw] = a;           // scattered 4B
        }

        if (!has_next) break;

        // H) convert + write next tile into LDS[buf^1]
        {
            bf16x8 h8, l8;
#pragma unroll
            for (int j = 0; j < 4; ++j) {
                h8[j] = f2bf(ea[j]);     l8[j] = f2bf(ea[j] - bf2f(h8[j]));
                h8[4 + j] = f2bf(eb[j]); l8[4 + j] = f2bf(eb[j] - bf2f(h8[4 + j]));
            }
            *(bf16x8*)&lds_hi[buf ^ 1][se][sd] = h8;
            *(bf16x8*)&lds_lo[buf ^ 1][se][sd] = l8;
        }

        // rotate pipeline state
        tile = next;
        pk = pkN;
        pkn = pkn2;
        qc0 = qn0; qc1 = qn1; kc0 = kn0; kc1 = kn1;
        buf ^= 1;
    }
}

// ---------------- K2b: per-node gather-reduce + W_fc matvec + residual + LN ----------
// 512 threads = 32 nodes/block: one W_fc LDS copy amortized 2x.
__global__ __launch_bounds__(512) void node_kernel(
    const int* __restrict__ base, const int* __restrict__ tgt_csr,
    const float* __restrict__ attn_csr, const short* __restrict__ Vb,
    const short* __restrict__ Wfcb, const float* __restrict__ inQ,
    const float* __restrict__ gamma, const float* __restrict__ beta,
    float* __restrict__ y)
{
    __shared__ short wlds[128 * 136];   // padded: stride 136 bf16
    __shared__ float alds[32 * 132];    // padded: stride 132 f32

    const int t = threadIdx.x;
    // stage W_fc: thread handles row r=t>>2, cols (t&3)*32..+31
    {
        const int r = t >> 2, colb = (t & 3) * 32;
#pragma unroll
        for (int c = 0; c < 4; ++c) {
            bf16x8 w = *(const bf16x8*)(Wfcb + r * 128 + colb + c * 8);
            *(bf16x8*)(&wlds[r * 136 + colb + c * 8]) = w;
        }
    }

    const int n_l = t >> 4;             // 0..31
    const int el  = t & 15;
    const int node = blockIdx.x * 32 + n_l;

    int b0 = 0, b1 = 0;
    if (node < NN) { b0 = base[node]; b1 = base[node + 1]; }
    float acc[8] = {};
    float csum = 0.f;
    const int h = el >> 2;

    int p = b0;
    for (; p + 8 <= b1; p += 8) {      // unroll x8 for memory-level parallelism
        int   tg[8];
        float aa[8];
        bf16x8 vv[8];
#pragma unroll
        for (int u = 0; u < 8; ++u) tg[u] = tgt_csr[p + u];
#pragma unroll
        for (int u = 0; u < 8; ++u) aa[u] = attn_csr[(size_t)(p + u) * 4 + h];
#pragma unroll
        for (int u = 0; u < 8; ++u) vv[u] = *(const bf16x8*)(Vb + (size_t)tg[u] * 128 + el * 8);
#pragma unroll
        for (int u = 0; u < 8; ++u) {
            csum += aa[u];
#pragma unroll
            for (int j = 0; j < 8; ++j) acc[j] += aa[u] * bf2f(vv[u][j]);
        }
    }
    for (; p < b1; ++p) {
        const int tg = tgt_csr[p];
        const float a = attn_csr[(size_t)p * 4 + h];
        bf16x8 v = *(const bf16x8*)(Vb + (size_t)tg * 128 + el * 8);
        csum += a;
#pragma unroll
        for (int j = 0; j < 8; ++j) acc[j] += a * bf2f(v[j]);
    }

    const float invc = 1.0f / (csum + 1e-8f);
#pragma unroll
    for (int j = 0; j < 8; ++j) alds[n_l * 132 + el * 8 + j] = acc[j] * invc;
    __syncthreads();

    float fc[8] = {};
#pragma unroll 4
    for (int k0 = 0; k0 < 128; k0 += 8) {
        float a8[8];
#pragma unroll
        for (int j = 0; j < 8; ++j) a8[j] = alds[n_l * 132 + k0 + j];
#pragma unroll
        for (int i = 0; i < 8; ++i) {
            const int d = el + 16 * i;
            bf16x8 w = *(const bf16x8*)(&wlds[d * 136 + k0]);
#pragma unroll
            for (int j = 0; j < 8; ++j) fc[i] += a8[j] * bf2f(w[j]);
        }
    }

    if (node < NN) {
        float x[8];
        float s = 0.f, s2 = 0.f;
#pragma unroll
        for (int i = 0; i < 8; ++i) {
            const int d = el + 16 * i;
            x[i] = fc[i] + inQ[(size_t)node * 128 + d];
            s += x[i]; s2 += x[i] * x[i];
        }
        s  += __shfl_xor(s, 1, 64);  s2 += __shfl_xor(s2, 1, 64);
        s  += __shfl_xor(s, 2, 64);  s2 += __shfl_xor(s2, 2, 64);
        s  += __shfl_xor(s, 4, 64);  s2 += __shfl_xor(s2, 4, 64);
        s  += __shfl_xor(s, 8, 64);  s2 += __shfl_xor(s2, 8, 64);
        const float mu = s * (1.0f / 128.0f);
        const float var = s2 * (1.0f / 128.0f) - mu * mu;
        const float rstd = rsqrtf(var + 1e-5f);
#pragma unroll
        for (int i = 0; i < 8; ++i) {
            const int d = el + 16 * i;
            y[(size_t)node * 128 + d] = (x[i] - mu) * rstd * gamma[d] + beta[d];
        }
    }
}

// ---------------- launcher ----------------
extern "C" void kernel_launch(void* const* d_in, const int* in_sizes, int n_in,
                              void* d_out, int out_size, void* d_ws, size_t ws_size,
                              hipStream_t stream) {
    const int*   eidx  = (const int*)d_in[0];
    const float* efeat = (const float*)d_in[1];
    const float* inQ   = (const float*)d_in[2];
    const float* inK   = (const float*)d_in[3];
    const float* inV   = (const float*)d_in[4];
    const float* WQ    = (const float*)d_in[5];
    const float* WK    = (const float*)d_in[6];
    const float* WV    = (const float*)d_in[7];
    const float* WE    = (const float*)d_in[8];
    const float* Wfc   = (const float*)d_in[9];
    const float* gamma = (const float*)d_in[10];
    const float* beta  = (const float*)d_in[11];

    float* y = (float*)d_out;
    float* attn_out = y + (size_t)NN * 128;   // 3,200,000

    // ws layout (bytes): same as R6-R10
    char* ws = (char*)d_ws;
    float* Qf      = (float*)ws;
    float* Kf      = (float*)(ws + 12800000);
    short* Vb      = (short*)(ws + 25600000);
    short* Whi     = (short*)(ws + 32000000);
    short* Wlo     = (short*)(ws + 32163840);
    float* attn_csr= (float*)(ws + 32262144);
    int*   tgt_csr = (int*)  (ws + 38662144);
    int4*  pack    = (int4*) (ws + 40262144);
    int*   deg     = (int*)  (ws + 46662144);
    int*   cnt     = (int*)  (ws + 46762496);
    int*   base    = (int*)  (ws + 46862848);

    hipMemsetAsync(deg, 0, 200704, stream);   // deg + cnt

    convert_hist_kernel<<<512 + (EN + 255) / 256, 256, 0, stream>>>(
        WQ, WK, WV, WE, Wfc, Whi, Wlo, eidx, deg);
    scan_kernel<<<1, 1024, 0, stream>>>(deg, base);
    scatter_kernel<<<(EN + 255) / 256, 256, 0, stream>>>(eidx, base, cnt, pack, tgt_csr);

    dim3 pg(391, 3);
    proj_all_kernel<<<pg, 256, 0, stream>>>(inQ, inK, inV, Whi, Wlo, Qf, Kf, Vb);

    edge_score_kernel<<<2048, 256, 0, stream>>>(pack, efeat, Qf, Kf,
                                                Whi + 3 * 16384, Wlo + 2 * 16384,
                                                attn_out, attn_csr);

    node_kernel<<<(NN + 31) / 32, 512, 0, stream>>>(base, tgt_csr, attn_csr, Vb,
                                                    Whi + 4 * 16384, inQ, gamma, beta, y);
}